// Round 12
// baseline (359.809 us; speedup 1.0000x reference)
//
#include <hip/hip_runtime.h>
#include <cmath>

#define BB 2
#define SS 2048
#define DMODEL 1024
#define NHEADS 16
#define DK 64
#define BSR (BB*SS)          // 4096 rows

typedef float f32x4 __attribute__((ext_vector_type(4)));
typedef short s16x8 __attribute__((ext_vector_type(8)));
typedef unsigned short ushort_t;
#define MFMA_BF16 __builtin_amdgcn_mfma_f32_16x16x32_bf16

__device__ __forceinline__ unsigned short f2bf(float x) {
    unsigned int u = __float_as_uint(x);
    unsigned int r = u + 0x7FFFu + ((u >> 16) & 1u);   // RNE
    return (unsigned short)(r >> 16);
}
__device__ __forceinline__ float bf2f(unsigned short h) {
    return __uint_as_float(((unsigned int)h) << 16);
}
__device__ __forceinline__ unsigned int pk2(float lo, float hi) {
    return (unsigned int)f2bf(lo) | ((unsigned int)f2bf(hi) << 16);
}

// Fragment-tiled layouts (lane-contiguous wave loads):
// Q/K (A/B-frag): [bh][s-tile(128)][chunk(2)][grp(4)][row16][8]
__device__ __forceinline__ size_t qk_idx(int bh, int s, int d) {
    return ((((size_t)bh * 128 + (s >> 4)) * 2 + (d >> 5)) * 4 + ((d >> 3) & 3)) * 128
           + (size_t)((s & 15) * 8 + (d & 7));
}
// V^T (A-frag for PV): [bh][k-chunk(64)][dt(4)][grp(4)][row16=d][8=k]
__device__ __forceinline__ size_t v_idx(int bh, int s, int d) {
    return ((((size_t)bh * 64 + (s >> 5)) * 4 + (d >> 4)) * 4 + ((s >> 3) & 3)) * 128
           + (size_t)((d & 15) * 8 + (s & 7));
}

// ---------------------------------------------------------------------------
// split: fp32 -> (hi, lo) bf16 for 3 activation tensors + 4 weight tensors.
// ---------------------------------------------------------------------------
__global__ __launch_bounds__(256)
void split_all(const float* __restrict__ q, const float* __restrict__ k,
               const float* __restrict__ v, const float* __restrict__ wq,
               const float* __restrict__ wk, const float* __restrict__ wv,
               const float* __restrict__ wo,
               ushort_t* qsh, ushort_t* qsl, ushort_t* ksh, ushort_t* ksl,
               ushort_t* vsh, ushort_t* vsl,
               ushort_t* wqh, ushort_t* wql, ushort_t* wkh, ushort_t* wkl,
               ushort_t* wvh, ushort_t* wvl, ushort_t* woh, ushort_t* wol)
{
    int blk = blockIdx.x;
    const float* src; ushort_t* dh; ushort_t* dl;
    if      (blk < 2048) { src = q;  dh = qsh; dl = qsl; }
    else if (blk < 4096) { src = k;  dh = ksh; dl = ksl; blk -= 2048; }
    else if (blk < 6144) { src = v;  dh = vsh; dl = vsl; blk -= 4096; }
    else if (blk < 6656) { src = wq; dh = wqh; dl = wql; blk -= 6144; }
    else if (blk < 7168) { src = wk; dh = wkh; dl = wkl; blk -= 6656; }
    else if (blk < 7680) { src = wv; dh = wvh; dl = wvl; blk -= 7168; }
    else                 { src = wo; dh = woh; dl = wol; blk -= 7680; }
    const size_t off = (size_t)blk * 2048 + threadIdx.x * 8;
    float4 a = *reinterpret_cast<const float4*>(src + off);
    float4 b = *reinterpret_cast<const float4*>(src + off + 4);
    float xs[8] = {a.x, a.y, a.z, a.w, b.x, b.y, b.z, b.w};
    s16x8 hi, lo;
#pragma unroll
    for (int i = 0; i < 8; ++i) {
        unsigned short h = f2bf(xs[i]);
        hi[i] = (short)h;
        lo[i] = (short)f2bf(xs[i] - bf2f(h));
    }
    *reinterpret_cast<s16x8*>(dh + off) = hi;
    *reinterpret_cast<s16x8*>(dl + off) = lo;
}

// ---------------------------------------------------------------------------
// sincos table: tab[s*32+j] = (cos, sin) of s * 10000^{-j/32}
// ---------------------------------------------------------------------------
__global__ __launch_bounds__(256)
void build_tab(float2* __restrict__ tab)
{
    const int t = blockIdx.x * 256 + threadIdx.x;    // 65536
    const int s = t >> 5, j = t & 31;
    const double l2 = 13.287712379549449 / 32.0;     // log2(10000)/32
    const float invf = (float)exp2(-(double)j * l2);
    const float ang = (float)s * invf;
    tab[t] = make_float2(cosf(ang), sinf(ang));
}

// ---------------------------------------------------------------------------
// Split-bf16 MFMA GEMM (R8-proven, UNCHANGED): C = A @ W^T, 3-term hi/lo.
// Tile 128x64x64, 256 thr = 4 waves. MODE 0: fp32 + bias. MODE 1: RoPE +
// hi/lo split into qk_idx fragment layout. MODE 2: bf16 V^T into v_idx layout.
// ---------------------------------------------------------------------------
template<int MODE>
__global__ __launch_bounds__(256)
void gemm_mfma(const ushort_t* __restrict__ Ah, const ushort_t* __restrict__ Al,
               const ushort_t* __restrict__ Bh, const ushort_t* __restrict__ Bl,
               float* __restrict__ outF, const float* __restrict__ bias,
               ushort_t* __restrict__ O1, ushort_t* __restrict__ O2,
               const float2* __restrict__ tab)
{
    __shared__ __align__(16) ushort_t smAh[128 * 64];
    __shared__ __align__(16) ushort_t smAl[128 * 64];
    __shared__ __align__(16) ushort_t smBh[64 * 64];
    __shared__ __align__(16) ushort_t smBl[64 * 64];

    const int tid = threadIdx.x;
    const int lane = tid & 63;
    const int w = tid >> 6;
    const int lane16 = lane & 15;
    const int grp = (lane >> 4) & 3;
    const int m0 = blockIdx.y * 128;
    const int n0 = blockIdx.x * 64;
    const int K = 1024;

    f32x4 acc[2][4];
#pragma unroll
    for (int a = 0; a < 2; ++a)
#pragma unroll
        for (int e = 0; e < 4; ++e) acc[a][e] = (f32x4){0.f, 0.f, 0.f, 0.f};

    for (int k0 = 0; k0 < K; k0 += 64) {
#pragma unroll
        for (int i = 0; i < 4; ++i) {
            const int c = tid + 256 * i;
            const int row = c >> 3, gs = c & 7;
            const int dst = row * 64 + ((gs ^ (row & 7)) * 8);
            const size_t src = (size_t)(m0 + row) * K + k0 + gs * 8;
            *reinterpret_cast<s16x8*>(&smAh[dst]) = *reinterpret_cast<const s16x8*>(&Ah[src]);
            *reinterpret_cast<s16x8*>(&smAl[dst]) = *reinterpret_cast<const s16x8*>(&Al[src]);
        }
#pragma unroll
        for (int i = 0; i < 2; ++i) {
            const int c = tid + 256 * i;
            const int row = c >> 3, gs = c & 7;
            const int dst = row * 64 + ((gs ^ (row & 7)) * 8);
            const size_t src = (size_t)(n0 + row) * K + k0 + gs * 8;
            *reinterpret_cast<s16x8*>(&smBh[dst]) = *reinterpret_cast<const s16x8*>(&Bh[src]);
            *reinterpret_cast<s16x8*>(&smBl[dst]) = *reinterpret_cast<const s16x8*>(&Bl[src]);
        }
        __syncthreads();
#pragma unroll
        for (int ks = 0; ks < 2; ++ks) {
            const int slotk = ks * 4 + grp;
            s16x8 afh[2], afl[2], bfh[4], bfl[4];
#pragma unroll
            for (int mt = 0; mt < 2; ++mt) {
                const int row = w * 32 + mt * 16 + lane16;
                const int off = row * 64 + ((slotk ^ (row & 7)) * 8);
                afh[mt] = *reinterpret_cast<const s16x8*>(&smAh[off]);
                afl[mt] = *reinterpret_cast<const s16x8*>(&smAl[off]);
            }
#pragma unroll
            for (int nt = 0; nt < 4; ++nt) {
                const int row = nt * 16 + lane16;
                const int off = row * 64 + ((slotk ^ (row & 7)) * 8);
                bfh[nt] = *reinterpret_cast<const s16x8*>(&smBh[off]);
                bfl[nt] = *reinterpret_cast<const s16x8*>(&smBl[off]);
            }
#pragma unroll
            for (int mt = 0; mt < 2; ++mt)
#pragma unroll
                for (int nt = 0; nt < 4; ++nt) {
                    acc[mt][nt] = MFMA_BF16(afh[mt], bfl[nt], acc[mt][nt], 0, 0, 0);
                    acc[mt][nt] = MFMA_BF16(afl[mt], bfh[nt], acc[mt][nt], 0, 0, 0);
                    acc[mt][nt] = MFMA_BF16(afh[mt], bfh[nt], acc[mt][nt], 0, 0, 0);
                }
        }
        __syncthreads();
    }

    if constexpr (MODE == 0) {
#pragma unroll
        for (int mt = 0; mt < 2; ++mt)
#pragma unroll
            for (int r = 0; r < 4; ++r) {
                const int m = m0 + w * 32 + mt * 16 + grp * 4 + r;
#pragma unroll
                for (int nt = 0; nt < 4; ++nt) {
                    const int n = n0 + nt * 16 + lane16;
                    outF[(size_t)m * 1024 + n] = acc[mt][nt][r] + bias[n];
                }
            }
    } else if constexpr (MODE == 1) {
        const int hh = blockIdx.x;               // N-tile == one head
#pragma unroll
        for (int mt = 0; mt < 2; ++mt)
#pragma unroll
            for (int r = 0; r < 4; ++r) {
                const int m = m0 + w * 32 + mt * 16 + grp * 4 + r;
                const int b = m >> 11, s = m & (SS - 1);
                const int bh = b * 16 + hh;
#pragma unroll
                for (int ntp = 0; ntp < 2; ++ntp) {
                    const int j = ntp * 16 + lane16;          // 0..31
                    const float2 cs = tab[s * 32 + j];
                    const float x1 = acc[mt][ntp][r], x2 = acc[mt][ntp + 2][r];
                    const float r1 = x1 * cs.x - x2 * cs.y;
                    const float r2 = x2 * cs.x + x1 * cs.y;
                    const size_t i1 = qk_idx(bh, s, j);
                    const size_t i2 = qk_idx(bh, s, j + 32);
                    const unsigned short h1 = f2bf(r1);
                    O1[i1] = h1;  O2[i1] = f2bf(r1 - bf2f(h1));
                    const unsigned short h2 = f2bf(r2);
                    O1[i2] = h2;  O2[i2] = f2bf(r2 - bf2f(h2));
                }
            }
    } else {
        const int hh = blockIdx.x;
#pragma unroll
        for (int mt = 0; mt < 2; ++mt)
#pragma unroll
            for (int r = 0; r < 4; ++r) {
                const int m = m0 + w * 32 + mt * 16 + grp * 4 + r;
                const int b = m >> 11, s = m & (SS - 1);
                const int bh = b * 16 + hh;
#pragma unroll
                for (int nt = 0; nt < 4; ++nt) {
                    const int d = nt * 16 + lane16;
                    O1[v_idx(bh, s, d)] = f2bf(acc[mt][nt][r]);
                }
            }
    }
}

// ---------------------------------------------------------------------------
// MFMA attention v7nt = R11's v6nt + (a) explicit 2-deep K prefetch (rolling
// kbuf, static idx under full unroll), (b) p packed to bf16 pairs right after
// exp (pp = 32 VGPR vs 64, makes room for kbuf). ctx path bit-identical (PV
// consumed bf16(p) before); attn store = bf16(p)*rinv (<=2^-9 rel, proven
// passing in R10 with identical absmax). nt stores kept from R11.
// ---------------------------------------------------------------------------
#define SCALE_L2E 0.180336879f    // (1/8) * log2(e)

__global__ __launch_bounds__(1024, 4)
void attn_v7(const ushort_t* __restrict__ Qf_h, const ushort_t* __restrict__ Qf_l,
             const ushort_t* __restrict__ Kf_h, const ushort_t* __restrict__ Kf_l,
             const ushort_t* __restrict__ Vf,
             float* __restrict__ attn, ushort_t* __restrict__ ctxh, ushort_t* __restrict__ ctxl)
{
    __shared__ __align__(16) float slots[8][32][68];   // 69,632 B ctx reduce
    __shared__ float lsum[16][32];
    __shared__ float rinvS[32];

    const int tid = threadIdx.x;
    const int lane = tid & 63;
    const int w = tid >> 6;              // 0..15
    const int lane16 = lane & 15;
    const int grp = lane >> 4;           // 0..3

    const int bid = blockIdx.x;
    const int idx = bid >> 3;                    // 0..255
    const int bh = (bid & 7) * 4 + (idx >> 6);   // 4 bh per XCD, sequential
    const int q0 = (idx & 63) * 32;

    // ---- Q fragments: 2 q-subtiles x 2 d-chunks, hi+lo ----
    s16x8 qh[2][2], ql[2][2];
#pragma unroll
    for (int qt = 0; qt < 2; ++qt) {
        const size_t qb = ((size_t)(bh * 128 + (q0 >> 4) + qt) * 2) * 512 + lane * 8;
        qh[qt][0] = *reinterpret_cast<const s16x8*>(Qf_h + qb);
        qh[qt][1] = *reinterpret_cast<const s16x8*>(Qf_h + qb + 512);
        ql[qt][0] = *reinterpret_cast<const s16x8*>(Qf_l + qb);
        ql[qt][1] = *reinterpret_cast<const s16x8*>(Qf_l + qb + 512);
    }

    // ---- QK^T with 2-deep K prefetch; fused exp + bf16 pack ----
    unsigned int pp[8][2][2];            // packed bf16 pairs of exp(scores)
    float lq[2] = {0.f, 0.f};
    s16x8 kbuf[2][4];                    // [slot][kh0,kh1,kl0,kl1]
#pragma unroll
    for (int s = 0; s < 2; ++s) {
        const size_t kb = ((size_t)(bh * 128 + w * 8 + s) * 2) * 512 + lane * 8;
        kbuf[s][0] = *reinterpret_cast<const s16x8*>(Kf_h + kb);
        kbuf[s][1] = *reinterpret_cast<const s16x8*>(Kf_h + kb + 512);
        kbuf[s][2] = *reinterpret_cast<const s16x8*>(Kf_l + kb);
        kbuf[s][3] = *reinterpret_cast<const s16x8*>(Kf_l + kb + 512);
    }
#pragma unroll
    for (int kt = 0; kt < 8; ++kt) {
        s16x8 nh0, nh1, nl0, nl1;
        if (kt < 6) {
            const size_t kn = ((size_t)(bh * 128 + w * 8 + kt + 2) * 2) * 512 + lane * 8;
            nh0 = *reinterpret_cast<const s16x8*>(Kf_h + kn);
            nh1 = *reinterpret_cast<const s16x8*>(Kf_h + kn + 512);
            nl0 = *reinterpret_cast<const s16x8*>(Kf_l + kn);
            nl1 = *reinterpret_cast<const s16x8*>(Kf_l + kn + 512);
        }
        const s16x8 kh0 = kbuf[kt & 1][0];
        const s16x8 kh1 = kbuf[kt & 1][1];
        const s16x8 kl0 = kbuf[kt & 1][2];
        const s16x8 kl1 = kbuf[kt & 1][3];
#pragma unroll
        for (int qt = 0; qt < 2; ++qt) {
            f32x4 t = {0.f, 0.f, 0.f, 0.f};
            t = MFMA_BF16(kh0, ql[qt][0], t, 0, 0, 0);
            t = MFMA_BF16(kh1, ql[qt][1], t, 0, 0, 0);
            t = MFMA_BF16(kl0, qh[qt][0], t, 0, 0, 0);
            t = MFMA_BF16(kl1, qh[qt][1], t, 0, 0, 0);
            t = MFMA_BF16(kh0, qh[qt][0], t, 0, 0, 0);
            t = MFMA_BF16(kh1, qh[qt][1], t, 0, 0, 0);
            const float e0 = exp2f(t[0] * SCALE_L2E);
            const float e1 = exp2f(t[1] * SCALE_L2E);
            const float e2 = exp2f(t[2] * SCALE_L2E);
            const float e3 = exp2f(t[3] * SCALE_L2E);
            lq[qt] += e0 + e1 + e2 + e3;
            pp[kt][qt][0] = pk2(e0, e1);
            pp[kt][qt][1] = pk2(e2, e3);
        }
        if (kt < 6) {
            kbuf[kt & 1][0] = nh0; kbuf[kt & 1][1] = nh1;
            kbuf[kt & 1][2] = nl0; kbuf[kt & 1][3] = nl1;
        }
    }

    // ---- cross-wave softmax denominators ----
#pragma unroll
    for (int qt = 0; qt < 2; ++qt) {
        lq[qt] += __shfl_xor(lq[qt], 16, 64);
        lq[qt] += __shfl_xor(lq[qt], 32, 64);
    }
    if (grp == 0) {
        lsum[w][lane16]      = lq[0];
        lsum[w][16 + lane16] = lq[1];
    }
    __syncthreads();                                   // b1
    float tot0 = 0.f, tot1 = 0.f;
#pragma unroll
    for (int w2 = 0; w2 < 16; ++w2) {
        tot0 += lsum[w2][lane16];
        tot1 += lsum[w2][16 + lane16];
    }
    const float rinv[2] = {1.0f / tot0, 1.0f / tot1};
    if (w == 0 && grp == 0) {
        rinvS[lane16]      = rinv[0];
        rinvS[16 + lane16] = rinv[1];
    }

    // ---- attn stores: unpack bf16 pairs, scale, NONTEMPORAL f32x4 ----
#pragma unroll
    for (int qt = 0; qt < 2; ++qt) {
        const size_t arow = ((size_t)bh * SS + q0 + qt * 16 + lane16) * SS + w * 128 + grp * 4;
#pragma unroll
        for (int kt = 0; kt < 8; ++kt) {
            const unsigned int u0 = pp[kt][qt][0];
            const unsigned int u1 = pp[kt][qt][1];
            f32x4 v4;
            v4[0] = __uint_as_float(u0 << 16) * rinv[qt];
            v4[1] = __uint_as_float(u0 & 0xffff0000u) * rinv[qt];
            v4[2] = __uint_as_float(u1 << 16) * rinv[qt];
            v4[3] = __uint_as_float(u1 & 0xffff0000u) * rinv[qt];
            __builtin_nontemporal_store(v4, reinterpret_cast<f32x4*>(&attn[arow + kt * 16]));
        }
    }

    // ---- PV: shfl redistribution directly on packed words ----
    f32x4 acc[4][2];
#pragma unroll
    for (int dt = 0; dt < 4; ++dt) {
        acc[dt][0] = (f32x4){0.f, 0.f, 0.f, 0.f};
        acc[dt][1] = (f32x4){0.f, 0.f, 0.f, 0.f};
    }
    const int src0 = lane16 + ((grp & 1) << 5);
    const int src1 = src0 + 16;
    const bool sel = (grp >> 1) != 0;
#pragma unroll
    for (int kc = 0; kc < 4; ++kc) {
        s16x8 bfr[2];
#pragma unroll
        for (int qt = 0; qt < 2; ++qt) {
            const unsigned int A0 = pp[2 * kc][qt][0];
            const unsigned int A1 = pp[2 * kc][qt][1];
            const unsigned int B0 = pp[2 * kc + 1][qt][0];
            const unsigned int B1 = pp[2 * kc + 1][qt][1];
            const unsigned int d0a = (unsigned int)__shfl((int)A0, src0, 64);
            const unsigned int d0b = (unsigned int)__shfl((int)B0, src0, 64);
            const unsigned int d1a = (unsigned int)__shfl((int)A1, src0, 64);
            const unsigned int d1b = (unsigned int)__shfl((int)B1, src0, 64);
            const unsigned int d2a = (unsigned int)__shfl((int)A0, src1, 64);
            const unsigned int d2b = (unsigned int)__shfl((int)B0, src1, 64);
            const unsigned int d3a = (unsigned int)__shfl((int)A1, src1, 64);
            const unsigned int d3b = (unsigned int)__shfl((int)B1, src1, 64);
            union { unsigned int u[4]; s16x8 v; } bu;
            bu.u[0] = sel ? d0b : d0a;
            bu.u[1] = sel ? d1b : d1a;
            bu.u[2] = sel ? d2b : d2a;
            bu.u[3] = sel ? d3b : d3a;
            bfr[qt] = bu.v;
        }
#pragma unroll
        for (int dt = 0; dt < 4; ++dt) {
            const s16x8 vf = *reinterpret_cast<const s16x8*>(
                &Vf[((size_t)(bh * 64 + w * 4 + kc) * 4 + dt) * 512 + lane * 8]);
            acc[dt][0] = MFMA_BF16(vf, bfr[0], acc[dt][0], 0, 0, 0);
            acc[dt][1] = MFMA_BF16(vf, bfr[1], acc[dt][1], 0, 0, 0);
        }
    }

    // ---- two-stage cross-wave ctx reduce ----
    if (w >= 8) {
        float* slot = &slots[w - 8][0][0];
#pragma unroll
        for (int dt = 0; dt < 4; ++dt)
#pragma unroll
            for (int qt = 0; qt < 2; ++qt) {
                f32x4 v4;
                v4[0] = acc[dt][qt][0]; v4[1] = acc[dt][qt][1];
                v4[2] = acc[dt][qt][2]; v4[3] = acc[dt][qt][3];
                *reinterpret_cast<f32x4*>(&slot[(qt * 16 + lane16) * 68 + dt * 16 + grp * 4]) = v4;
            }
    }
    __syncthreads();                                   // b2
    if (w < 8) {
        float* slot = &slots[w][0][0];
#pragma unroll
        for (int dt = 0; dt < 4; ++dt)
#pragma unroll
            for (int qt = 0; qt < 2; ++qt) {
                f32x4* pq = reinterpret_cast<f32x4*>(&slot[(qt * 16 + lane16) * 68 + dt * 16 + grp * 4]);
                f32x4 o = *pq;
                o[0] += acc[dt][qt][0]; o[1] += acc[dt][qt][1];
                o[2] += acc[dt][qt][2]; o[3] += acc[dt][qt][3];
                *pq = o;
            }
    }
    __syncthreads();                                   // b3

    // ---- final: sum 8 slots, normalize, split hi/lo, write ctx ----
    {
        const int b = bh >> 4, h = bh & 15;
        const int q = tid >> 5;              // 0..31
        const int dp = (tid & 31) * 2;       // 0..62
        float s0 = 0.f, s1 = 0.f;
#pragma unroll
        for (int s = 0; s < 8; ++s) {
            const float2 v = *reinterpret_cast<const float2*>(&slots[s][q][dp]);
            s0 += v.x; s1 += v.y;
        }
        const float rv = rinvS[q];
        s0 *= rv; s1 *= rv;
        const size_t co = ((size_t)b * SS + q0 + q) * DMODEL + h * DK + dp;
        const unsigned short h0 = f2bf(s0);
        const unsigned short l0 = f2bf(s0 - bf2f(h0));
        const unsigned short h1 = f2bf(s1);
        const unsigned short l1 = f2bf(s1 - bf2f(h1));
        *reinterpret_cast<unsigned int*>(ctxh + co) = (unsigned int)h0 | ((unsigned int)h1 << 16);
        *reinterpret_cast<unsigned int*>(ctxl + co) = (unsigned int)l0 | ((unsigned int)l1 << 16);
    }
}

// ---------------------------------------------------------------------------
extern "C" void kernel_launch(void* const* d_in, const int* in_sizes, int n_in,
                              void* d_out, int out_size, void* d_ws, size_t ws_size,
                              hipStream_t stream)
{
    const float* query = (const float*)d_in[0];
    const float* key   = (const float*)d_in[1];
    const float* value = (const float*)d_in[2];
    const float* Wq    = (const float*)d_in[3];
    const float* Wk    = (const float*)d_in[4];
    const float* Wv    = (const float*)d_in[5];
    const float* Wo    = (const float*)d_in[6];
    const float* bo    = (const float*)d_in[7];

    float* out   = (float*)d_out;
    float* attnO = out + (size_t)BSR * DMODEL;

    const size_t NPROJ = (size_t)BSR * DMODEL;      // 4,194,304
    const size_t NW    = (size_t)DMODEL * DMODEL;   // 1,048,576

    char* p = (char*)d_ws;
    float2* tab = (float2*)p;                 p += 1 << 20;
    ushort_t* qsh = (ushort_t*)p;             p += NPROJ * 2;
    ushort_t* qsl = (ushort_t*)p;             p += NPROJ * 2;
    ushort_t* ksh = (ushort_t*)p;             p += NPROJ * 2;
    ushort_t* ksl = (ushort_t*)p;             p += NPROJ * 2;
    ushort_t* vsh = (ushort_t*)p;             p += NPROJ * 2;
    ushort_t* vsl = (ushort_t*)p;             p += NPROJ * 2;
    ushort_t* wqh = (ushort_t*)p;             p += NW * 2;
    ushort_t* wql = (ushort_t*)p;             p += NW * 2;
    ushort_t* wkh = (ushort_t*)p;             p += NW * 2;
    ushort_t* wkl = (ushort_t*)p;             p += NW * 2;
    ushort_t* wvh = (ushort_t*)p;             p += NW * 2;
    ushort_t* wvl = (ushort_t*)p;             p += NW * 2;
    ushort_t* woh = (ushort_t*)p;             p += NW * 2;
    ushort_t* wol = (ushort_t*)p;             p += NW * 2;
    ushort_t* Vt  = (ushort_t*)p;             p += NPROJ * 2;
    // Aliases (sequential lifetimes): Q-GEMM out <- v-source; K-GEMM out <-
    // q-source; attn ctx out <- k-source.
    ushort_t* Qhi = vsh; ushort_t* Qlo = vsl;
    ushort_t* Khi = qsh; ushort_t* Klo = qsl;
    ushort_t* ctxhC = ksh; ushort_t* ctxlC = ksl;

    split_all<<<8192, 256, 0, stream>>>(query, key, value, Wq, Wk, Wv, Wo,
                                        qsh, qsl, ksh, ksl, vsh, vsl,
                                        wqh, wql, wkh, wkl, wvh, wvl, woh, wol);
    build_tab<<<256, 256, 0, stream>>>(tab);

    const dim3 ggrid(DMODEL / 64, BSR / 128);       // (16, 32)
    gemm_mfma<2><<<ggrid, 256, 0, stream>>>(vsh, vsl, wvh, wvl, nullptr, nullptr, Vt, nullptr, nullptr);
    gemm_mfma<1><<<ggrid, 256, 0, stream>>>(qsh, qsl, wqh, wql, nullptr, nullptr, Qhi, Qlo, tab);
    gemm_mfma<1><<<ggrid, 256, 0, stream>>>(ksh, ksl, wkh, wkl, nullptr, nullptr, Khi, Klo, tab);

    attn_v7<<<dim3(2048), 1024, 0, stream>>>(Qhi, Qlo, Khi, Klo, Vt, attnO, ctxhC, ctxlC);

    gemm_mfma<0><<<ggrid, 256, 0, stream>>>(ctxhC, ctxlC, woh, wol, out, bo, nullptr, nullptr, nullptr);
}

// Round 13
// 346.699 us; speedup vs baseline: 1.0378x; 1.0378x over previous
//
#include <hip/hip_runtime.h>
#include <cmath>

#define BB 2
#define SS 2048
#define DMODEL 1024
#define NHEADS 16
#define DK 64
#define BSR (BB*SS)          // 4096 rows

typedef float f32x4 __attribute__((ext_vector_type(4)));
typedef short s16x8 __attribute__((ext_vector_type(8)));
typedef unsigned short ushort_t;
#define MFMA_BF16 __builtin_amdgcn_mfma_f32_16x16x32_bf16

__device__ __forceinline__ unsigned short f2bf(float x) {
    unsigned int u = __float_as_uint(x);
    unsigned int r = u + 0x7FFFu + ((u >> 16) & 1u);   // RNE
    return (unsigned short)(r >> 16);
}
__device__ __forceinline__ float bf2f(unsigned short h) {
    return __uint_as_float(((unsigned int)h) << 16);
}
__device__ __forceinline__ unsigned int pk2(float lo, float hi) {
    return (unsigned int)f2bf(lo) | ((unsigned int)f2bf(hi) << 16);
}

// Fragment-tiled layouts (lane-contiguous wave loads):
// Q/K (A/B-frag): [bh][s-tile(128)][chunk(2)][grp(4)][row16][8]
__device__ __forceinline__ size_t qk_idx(int bh, int s, int d) {
    return ((((size_t)bh * 128 + (s >> 4)) * 2 + (d >> 5)) * 4 + ((d >> 3) & 3)) * 128
           + (size_t)((s & 15) * 8 + (d & 7));
}
// V^T (A-frag for PV): [bh][k-chunk(64)][dt(4)][grp(4)][row16=d][8=k]
__device__ __forceinline__ size_t v_idx(int bh, int s, int d) {
    return ((((size_t)bh * 64 + (s >> 5)) * 4 + (d >> 4)) * 4 + ((s >> 3) & 3)) * 128
           + (size_t)((d & 15) * 8 + (s & 7));
}

// ---------------------------------------------------------------------------
// split+tab: fp32 -> (hi,lo) bf16 for 3 activations + 4 weights; last 256
// blocks build the RoPE sincos table (merged to save a launch).
// ---------------------------------------------------------------------------
__global__ __launch_bounds__(256)
void split_tab(const float* __restrict__ q, const float* __restrict__ k,
               const float* __restrict__ v, const float* __restrict__ wq,
               const float* __restrict__ wk, const float* __restrict__ wv,
               const float* __restrict__ wo,
               ushort_t* qsh, ushort_t* qsl, ushort_t* ksh, ushort_t* ksl,
               ushort_t* vsh, ushort_t* vsl,
               ushort_t* wqh, ushort_t* wql, ushort_t* wkh, ushort_t* wkl,
               ushort_t* wvh, ushort_t* wvl, ushort_t* woh, ushort_t* wol,
               float2* __restrict__ tab)
{
    int blk = blockIdx.x;
    if (blk >= 8192) {                       // ---- tab tail ----
        const int t = (blk - 8192) * 256 + threadIdx.x;    // 65536
        const int s = t >> 5, j = t & 31;
        const double l2 = 13.287712379549449 / 32.0;       // log2(10000)/32
        const float invf = (float)exp2(-(double)j * l2);
        const float ang = (float)s * invf;
        tab[t] = make_float2(cosf(ang), sinf(ang));
        return;
    }
    const float* src; ushort_t* dh; ushort_t* dl;
    if      (blk < 2048) { src = q;  dh = qsh; dl = qsl; }
    else if (blk < 4096) { src = k;  dh = ksh; dl = ksl; blk -= 2048; }
    else if (blk < 6144) { src = v;  dh = vsh; dl = vsl; blk -= 4096; }
    else if (blk < 6656) { src = wq; dh = wqh; dl = wql; blk -= 6144; }
    else if (blk < 7168) { src = wk; dh = wkh; dl = wkl; blk -= 6656; }
    else if (blk < 7680) { src = wv; dh = wvh; dl = wvl; blk -= 7168; }
    else                 { src = wo; dh = woh; dl = wol; blk -= 7680; }
    const size_t off = (size_t)blk * 2048 + threadIdx.x * 8;
    float4 a = *reinterpret_cast<const float4*>(src + off);
    float4 b = *reinterpret_cast<const float4*>(src + off + 4);
    float xs[8] = {a.x, a.y, a.z, a.w, b.x, b.y, b.z, b.w};
    s16x8 hi, lo;
#pragma unroll
    for (int i = 0; i < 8; ++i) {
        unsigned short h = f2bf(xs[i]);
        hi[i] = (short)h;
        lo[i] = (short)f2bf(xs[i] - bf2f(h));
    }
    *reinterpret_cast<s16x8*>(dh + off) = hi;
    *reinterpret_cast<s16x8*>(dl + off) = lo;
}

// ---------------------------------------------------------------------------
// Merged QKV split-bf16 MFMA GEMM: grid (16, 32, 3); z=0: V -> Vt (v_idx),
// z=1: Q -> RoPE qk_idx, z=2: K -> RoPE qk_idx. K-loop identical to the
// R8-proven 128x64x64 tile, 256 thr = 4 waves. 1536 blocks total ->
// 3 blocks/CU (48KB LDS each) = 12 waves/CU vs 8 when launched separately,
// and two launch drains removed.
// ---------------------------------------------------------------------------
__global__ __launch_bounds__(256)
void qkv_gemm(const ushort_t* __restrict__ qsh, const ushort_t* __restrict__ qsl,
              const ushort_t* __restrict__ ksh, const ushort_t* __restrict__ ksl,
              const ushort_t* __restrict__ vsh, const ushort_t* __restrict__ vsl,
              const ushort_t* __restrict__ wqh, const ushort_t* __restrict__ wql,
              const ushort_t* __restrict__ wkh, const ushort_t* __restrict__ wkl,
              const ushort_t* __restrict__ wvh, const ushort_t* __restrict__ wvl,
              ushort_t* __restrict__ Qhi, ushort_t* __restrict__ Qlo,
              ushort_t* __restrict__ Khi, ushort_t* __restrict__ Klo,
              ushort_t* __restrict__ Vt,
              const float2* __restrict__ tab)
{
    __shared__ __align__(16) ushort_t smAh[128 * 64];
    __shared__ __align__(16) ushort_t smAl[128 * 64];
    __shared__ __align__(16) ushort_t smBh[64 * 64];
    __shared__ __align__(16) ushort_t smBl[64 * 64];

    const int tid = threadIdx.x;
    const int lane = tid & 63;
    const int w = tid >> 6;
    const int lane16 = lane & 15;
    const int grp = (lane >> 4) & 3;
    const int m0 = blockIdx.y * 128;
    const int n0 = blockIdx.x * 64;
    const int z  = blockIdx.z;           // 0=V, 1=Q, 2=K
    const int K = 1024;

    const ushort_t* Ah = (z == 0) ? vsh : ((z == 1) ? qsh : ksh);
    const ushort_t* Al = (z == 0) ? vsl : ((z == 1) ? qsl : ksl);
    const ushort_t* Bh = (z == 0) ? wvh : ((z == 1) ? wqh : wkh);
    const ushort_t* Bl = (z == 0) ? wvl : ((z == 1) ? wql : wkl);

    f32x4 acc[2][4];
#pragma unroll
    for (int a = 0; a < 2; ++a)
#pragma unroll
        for (int e = 0; e < 4; ++e) acc[a][e] = (f32x4){0.f, 0.f, 0.f, 0.f};

    for (int k0 = 0; k0 < K; k0 += 64) {
#pragma unroll
        for (int i = 0; i < 4; ++i) {
            const int c = tid + 256 * i;
            const int row = c >> 3, gs = c & 7;
            const int dst = row * 64 + ((gs ^ (row & 7)) * 8);
            const size_t src = (size_t)(m0 + row) * K + k0 + gs * 8;
            *reinterpret_cast<s16x8*>(&smAh[dst]) = *reinterpret_cast<const s16x8*>(&Ah[src]);
            *reinterpret_cast<s16x8*>(&smAl[dst]) = *reinterpret_cast<const s16x8*>(&Al[src]);
        }
#pragma unroll
        for (int i = 0; i < 2; ++i) {
            const int c = tid + 256 * i;
            const int row = c >> 3, gs = c & 7;
            const int dst = row * 64 + ((gs ^ (row & 7)) * 8);
            const size_t src = (size_t)(n0 + row) * K + k0 + gs * 8;
            *reinterpret_cast<s16x8*>(&smBh[dst]) = *reinterpret_cast<const s16x8*>(&Bh[src]);
            *reinterpret_cast<s16x8*>(&smBl[dst]) = *reinterpret_cast<const s16x8*>(&Bl[src]);
        }
        __syncthreads();
#pragma unroll
        for (int ks = 0; ks < 2; ++ks) {
            const int slotk = ks * 4 + grp;
            s16x8 afh[2], afl[2], bfh[4], bfl[4];
#pragma unroll
            for (int mt = 0; mt < 2; ++mt) {
                const int row = w * 32 + mt * 16 + lane16;
                const int off = row * 64 + ((slotk ^ (row & 7)) * 8);
                afh[mt] = *reinterpret_cast<const s16x8*>(&smAh[off]);
                afl[mt] = *reinterpret_cast<const s16x8*>(&smAl[off]);
            }
#pragma unroll
            for (int nt = 0; nt < 4; ++nt) {
                const int row = nt * 16 + lane16;
                const int off = row * 64 + ((slotk ^ (row & 7)) * 8);
                bfh[nt] = *reinterpret_cast<const s16x8*>(&smBh[off]);
                bfl[nt] = *reinterpret_cast<const s16x8*>(&smBl[off]);
            }
#pragma unroll
            for (int mt = 0; mt < 2; ++mt)
#pragma unroll
                for (int nt = 0; nt < 4; ++nt) {
                    acc[mt][nt] = MFMA_BF16(afh[mt], bfl[nt], acc[mt][nt], 0, 0, 0);
                    acc[mt][nt] = MFMA_BF16(afl[mt], bfh[nt], acc[mt][nt], 0, 0, 0);
                    acc[mt][nt] = MFMA_BF16(afh[mt], bfh[nt], acc[mt][nt], 0, 0, 0);
                }
        }
        __syncthreads();
    }

    const int hh = blockIdx.x;               // N-tile == one head
    if (z == 0) {
        // V: bf16 V^T into v_idx layout
#pragma unroll
        for (int mt = 0; mt < 2; ++mt)
#pragma unroll
            for (int r = 0; r < 4; ++r) {
                const int m = m0 + w * 32 + mt * 16 + grp * 4 + r;
                const int b = m >> 11, s = m & (SS - 1);
                const int bh = b * 16 + hh;
#pragma unroll
                for (int nt = 0; nt < 4; ++nt) {
                    const int d = nt * 16 + lane16;
                    Vt[v_idx(bh, s, d)] = f2bf(acc[mt][nt][r]);
                }
            }
    } else {
        ushort_t* O1 = (z == 1) ? Qhi : Khi;
        ushort_t* O2 = (z == 1) ? Qlo : Klo;
#pragma unroll
        for (int mt = 0; mt < 2; ++mt)
#pragma unroll
            for (int r = 0; r < 4; ++r) {
                const int m = m0 + w * 32 + mt * 16 + grp * 4 + r;
                const int b = m >> 11, s = m & (SS - 1);
                const int bh = b * 16 + hh;
#pragma unroll
                for (int ntp = 0; ntp < 2; ++ntp) {
                    const int j = ntp * 16 + lane16;          // 0..31
                    const float2 cs = tab[s * 32 + j];
                    const float x1 = acc[mt][ntp][r], x2 = acc[mt][ntp + 2][r];
                    const float r1 = x1 * cs.x - x2 * cs.y;
                    const float r2 = x2 * cs.x + x1 * cs.y;
                    const size_t i1 = qk_idx(bh, s, j);
                    const size_t i2 = qk_idx(bh, s, j + 32);
                    const unsigned short h1 = f2bf(r1);
                    O1[i1] = h1;  O2[i1] = f2bf(r1 - bf2f(h1));
                    const unsigned short h2 = f2bf(r2);
                    O1[i2] = h2;  O2[i2] = f2bf(r2 - bf2f(h2));
                }
            }
    }
}

// ---------------------------------------------------------------------------
// Out-projection GEMM (R8-proven shape): fp32 out + bias.
// ---------------------------------------------------------------------------
__global__ __launch_bounds__(256)
void gemm_out(const ushort_t* __restrict__ Ah, const ushort_t* __restrict__ Al,
              const ushort_t* __restrict__ Bh, const ushort_t* __restrict__ Bl,
              float* __restrict__ outF, const float* __restrict__ bias)
{
    __shared__ __align__(16) ushort_t smAh[128 * 64];
    __shared__ __align__(16) ushort_t smAl[128 * 64];
    __shared__ __align__(16) ushort_t smBh[64 * 64];
    __shared__ __align__(16) ushort_t smBl[64 * 64];

    const int tid = threadIdx.x;
    const int lane = tid & 63;
    const int w = tid >> 6;
    const int lane16 = lane & 15;
    const int grp = (lane >> 4) & 3;
    const int m0 = blockIdx.y * 128;
    const int n0 = blockIdx.x * 64;
    const int K = 1024;

    f32x4 acc[2][4];
#pragma unroll
    for (int a = 0; a < 2; ++a)
#pragma unroll
        for (int e = 0; e < 4; ++e) acc[a][e] = (f32x4){0.f, 0.f, 0.f, 0.f};

    for (int k0 = 0; k0 < K; k0 += 64) {
#pragma unroll
        for (int i = 0; i < 4; ++i) {
            const int c = tid + 256 * i;
            const int row = c >> 3, gs = c & 7;
            const int dst = row * 64 + ((gs ^ (row & 7)) * 8);
            const size_t src = (size_t)(m0 + row) * K + k0 + gs * 8;
            *reinterpret_cast<s16x8*>(&smAh[dst]) = *reinterpret_cast<const s16x8*>(&Ah[src]);
            *reinterpret_cast<s16x8*>(&smAl[dst]) = *reinterpret_cast<const s16x8*>(&Al[src]);
        }
#pragma unroll
        for (int i = 0; i < 2; ++i) {
            const int c = tid + 256 * i;
            const int row = c >> 3, gs = c & 7;
            const int dst = row * 64 + ((gs ^ (row & 7)) * 8);
            const size_t src = (size_t)(n0 + row) * K + k0 + gs * 8;
            *reinterpret_cast<s16x8*>(&smBh[dst]) = *reinterpret_cast<const s16x8*>(&Bh[src]);
            *reinterpret_cast<s16x8*>(&smBl[dst]) = *reinterpret_cast<const s16x8*>(&Bl[src]);
        }
        __syncthreads();
#pragma unroll
        for (int ks = 0; ks < 2; ++ks) {
            const int slotk = ks * 4 + grp;
            s16x8 afh[2], afl[2], bfh[4], bfl[4];
#pragma unroll
            for (int mt = 0; mt < 2; ++mt) {
                const int row = w * 32 + mt * 16 + lane16;
                const int off = row * 64 + ((slotk ^ (row & 7)) * 8);
                afh[mt] = *reinterpret_cast<const s16x8*>(&smAh[off]);
                afl[mt] = *reinterpret_cast<const s16x8*>(&smAl[off]);
            }
#pragma unroll
            for (int nt = 0; nt < 4; ++nt) {
                const int row = nt * 16 + lane16;
                const int off = row * 64 + ((slotk ^ (row & 7)) * 8);
                bfh[nt] = *reinterpret_cast<const s16x8*>(&smBh[off]);
                bfl[nt] = *reinterpret_cast<const s16x8*>(&smBl[off]);
            }
#pragma unroll
            for (int mt = 0; mt < 2; ++mt)
#pragma unroll
                for (int nt = 0; nt < 4; ++nt) {
                    acc[mt][nt] = MFMA_BF16(afh[mt], bfl[nt], acc[mt][nt], 0, 0, 0);
                    acc[mt][nt] = MFMA_BF16(afl[mt], bfh[nt], acc[mt][nt], 0, 0, 0);
                    acc[mt][nt] = MFMA_BF16(afh[mt], bfh[nt], acc[mt][nt], 0, 0, 0);
                }
        }
        __syncthreads();
    }

#pragma unroll
    for (int mt = 0; mt < 2; ++mt)
#pragma unroll
        for (int r = 0; r < 4; ++r) {
            const int m = m0 + w * 32 + mt * 16 + grp * 4 + r;
#pragma unroll
            for (int nt = 0; nt < 4; ++nt) {
                const int n = n0 + nt * 16 + lane16;
                outF[(size_t)m * 1024 + n] = acc[mt][nt][r] + bias[n];
            }
        }
}

// ---------------------------------------------------------------------------
// MFMA attention v6nt (R11 winner, UNCHANGED): q-tile 32, 16 waves, no-max
// softmax, fragment-tiled operands, NONTEMPORAL attn stores (L2 bypass).
// ---------------------------------------------------------------------------
#define SCALE_L2E 0.180336879f    // (1/8) * log2(e)

__global__ __launch_bounds__(1024, 4)
void attn_v6(const ushort_t* __restrict__ Qf_h, const ushort_t* __restrict__ Qf_l,
             const ushort_t* __restrict__ Kf_h, const ushort_t* __restrict__ Kf_l,
             const ushort_t* __restrict__ Vf,
             float* __restrict__ attn, ushort_t* __restrict__ ctxh, ushort_t* __restrict__ ctxl)
{
    __shared__ __align__(16) float slots[8][32][68];   // 69,632 B ctx reduce
    __shared__ float lsum[16][32];
    __shared__ float rinvS[32];

    const int tid = threadIdx.x;
    const int lane = tid & 63;
    const int w = tid >> 6;              // 0..15
    const int lane16 = lane & 15;
    const int grp = lane >> 4;           // 0..3

    const int bid = blockIdx.x;
    const int idx = bid >> 3;                    // 0..255
    const int bh = (bid & 7) * 4 + (idx >> 6);   // 4 bh per XCD, sequential
    const int q0 = (idx & 63) * 32;

    s16x8 qh[2][2], ql[2][2];
#pragma unroll
    for (int qt = 0; qt < 2; ++qt) {
        const size_t qb = ((size_t)(bh * 128 + (q0 >> 4) + qt) * 2) * 512 + lane * 8;
        qh[qt][0] = *reinterpret_cast<const s16x8*>(Qf_h + qb);
        qh[qt][1] = *reinterpret_cast<const s16x8*>(Qf_h + qb + 512);
        ql[qt][0] = *reinterpret_cast<const s16x8*>(Qf_l + qb);
        ql[qt][1] = *reinterpret_cast<const s16x8*>(Qf_l + qb + 512);
    }

    f32x4 p[8][2];
#pragma unroll
    for (int kt = 0; kt < 8; ++kt) {
        const size_t kb = ((size_t)(bh * 128 + w * 8 + kt) * 2) * 512 + lane * 8;
        const s16x8 kh0 = *reinterpret_cast<const s16x8*>(Kf_h + kb);
        const s16x8 kh1 = *reinterpret_cast<const s16x8*>(Kf_h + kb + 512);
        const s16x8 kl0 = *reinterpret_cast<const s16x8*>(Kf_l + kb);
        const s16x8 kl1 = *reinterpret_cast<const s16x8*>(Kf_l + kb + 512);
#pragma unroll
        for (int qt = 0; qt < 2; ++qt) {
            f32x4 t = {0.f, 0.f, 0.f, 0.f};
            t = MFMA_BF16(kh0, ql[qt][0], t, 0, 0, 0);
            t = MFMA_BF16(kh1, ql[qt][1], t, 0, 0, 0);
            t = MFMA_BF16(kl0, qh[qt][0], t, 0, 0, 0);
            t = MFMA_BF16(kl1, qh[qt][1], t, 0, 0, 0);
            t = MFMA_BF16(kh0, qh[qt][0], t, 0, 0, 0);
            t = MFMA_BF16(kh1, qh[qt][1], t, 0, 0, 0);
            p[kt][qt] = t;
        }
    }

    float lq[2] = {0.f, 0.f};
#pragma unroll
    for (int kt = 0; kt < 8; ++kt)
#pragma unroll
        for (int qt = 0; qt < 2; ++qt)
#pragma unroll
            for (int r = 0; r < 4; ++r) {
                const float e = exp2f(p[kt][qt][r] * SCALE_L2E);
                p[kt][qt][r] = e;
                lq[qt] += e;
            }
#pragma unroll
    for (int qt = 0; qt < 2; ++qt) {
        lq[qt] += __shfl_xor(lq[qt], 16, 64);
        lq[qt] += __shfl_xor(lq[qt], 32, 64);
    }
    if (grp == 0) {
        lsum[w][lane16]      = lq[0];
        lsum[w][16 + lane16] = lq[1];
    }
    __syncthreads();                                   // b1
    float tot0 = 0.f, tot1 = 0.f;
#pragma unroll
    for (int w2 = 0; w2 < 16; ++w2) {
        tot0 += lsum[w2][lane16];
        tot1 += lsum[w2][16 + lane16];
    }
    const float rinv[2] = {1.0f / tot0, 1.0f / tot1};
    if (w == 0 && grp == 0) {
        rinvS[lane16]      = rinv[0];
        rinvS[16 + lane16] = rinv[1];
    }

    // ---- attn stores: direct f32x4, NONTEMPORAL (bypass L2) ----
#pragma unroll
    for (int qt = 0; qt < 2; ++qt) {
        const size_t arow = ((size_t)bh * SS + q0 + qt * 16 + lane16) * SS + w * 128 + grp * 4;
#pragma unroll
        for (int kt = 0; kt < 8; ++kt) {
            f32x4 v4;
            v4[0] = p[kt][qt][0] * rinv[qt]; v4[1] = p[kt][qt][1] * rinv[qt];
            v4[2] = p[kt][qt][2] * rinv[qt]; v4[3] = p[kt][qt][3] * rinv[qt];
            __builtin_nontemporal_store(v4, reinterpret_cast<f32x4*>(&attn[arow + kt * 16]));
        }
    }

    // ---- PV: in-register P^T redistribution (validated shfl mapping) ----
    f32x4 acc[4][2];
#pragma unroll
    for (int dt = 0; dt < 4; ++dt) {
        acc[dt][0] = (f32x4){0.f, 0.f, 0.f, 0.f};
        acc[dt][1] = (f32x4){0.f, 0.f, 0.f, 0.f};
    }
    const int src0 = lane16 + ((grp & 1) << 5);
    const int src1 = src0 + 16;
    const bool sel = (grp >> 1) != 0;
#pragma unroll
    for (int kc = 0; kc < 4; ++kc) {
        s16x8 bfr[2];
#pragma unroll
        for (int qt = 0; qt < 2; ++qt) {
            const unsigned int A0 = pk2(p[2*kc][qt][0],   p[2*kc][qt][1]);
            const unsigned int A1 = pk2(p[2*kc][qt][2],   p[2*kc][qt][3]);
            const unsigned int B0 = pk2(p[2*kc+1][qt][0], p[2*kc+1][qt][1]);
            const unsigned int B1 = pk2(p[2*kc+1][qt][2], p[2*kc+1][qt][3]);
            const unsigned int d0a = (unsigned int)__shfl((int)A0, src0, 64);
            const unsigned int d0b = (unsigned int)__shfl((int)B0, src0, 64);
            const unsigned int d1a = (unsigned int)__shfl((int)A1, src0, 64);
            const unsigned int d1b = (unsigned int)__shfl((int)B1, src0, 64);
            const unsigned int d2a = (unsigned int)__shfl((int)A0, src1, 64);
            const unsigned int d2b = (unsigned int)__shfl((int)B0, src1, 64);
            const unsigned int d3a = (unsigned int)__shfl((int)A1, src1, 64);
            const unsigned int d3b = (unsigned int)__shfl((int)B1, src1, 64);
            union { unsigned int u[4]; s16x8 v; } bu;
            bu.u[0] = sel ? d0b : d0a;
            bu.u[1] = sel ? d1b : d1a;
            bu.u[2] = sel ? d2b : d2a;
            bu.u[3] = sel ? d3b : d3a;
            bfr[qt] = bu.v;
        }
#pragma unroll
        for (int dt = 0; dt < 4; ++dt) {
            const s16x8 vf = *reinterpret_cast<const s16x8*>(
                &Vf[((size_t)(bh * 64 + w * 4 + kc) * 4 + dt) * 512 + lane * 8]);
            acc[dt][0] = MFMA_BF16(vf, bfr[0], acc[dt][0], 0, 0, 0);
            acc[dt][1] = MFMA_BF16(vf, bfr[1], acc[dt][1], 0, 0, 0);
        }
    }

    // ---- two-stage cross-wave ctx reduce ----
    if (w >= 8) {
        float* slot = &slots[w - 8][0][0];
#pragma unroll
        for (int dt = 0; dt < 4; ++dt)
#pragma unroll
            for (int qt = 0; qt < 2; ++qt) {
                f32x4 v4;
                v4[0] = acc[dt][qt][0]; v4[1] = acc[dt][qt][1];
                v4[2] = acc[dt][qt][2]; v4[3] = acc[dt][qt][3];
                *reinterpret_cast<f32x4*>(&slot[(qt * 16 + lane16) * 68 + dt * 16 + grp * 4]) = v4;
            }
    }
    __syncthreads();                                   // b2
    if (w < 8) {
        float* slot = &slots[w][0][0];
#pragma unroll
        for (int dt = 0; dt < 4; ++dt)
#pragma unroll
            for (int qt = 0; qt < 2; ++qt) {
                f32x4* pp = reinterpret_cast<f32x4*>(&slot[(qt * 16 + lane16) * 68 + dt * 16 + grp * 4]);
                f32x4 o = *pp;
                o[0] += acc[dt][qt][0]; o[1] += acc[dt][qt][1];
                o[2] += acc[dt][qt][2]; o[3] += acc[dt][qt][3];
                *pp = o;
            }
    }
    __syncthreads();                                   // b3

    {
        const int b = bh >> 4, h = bh & 15;
        const int q = tid >> 5;              // 0..31
        const int dp = (tid & 31) * 2;       // 0..62
        float s0 = 0.f, s1 = 0.f;
#pragma unroll
        for (int s = 0; s < 8; ++s) {
            const float2 v = *reinterpret_cast<const float2*>(&slots[s][q][dp]);
            s0 += v.x; s1 += v.y;
        }
        const float rv = rinvS[q];
        s0 *= rv; s1 *= rv;
        const size_t co = ((size_t)b * SS + q0 + q) * DMODEL + h * DK + dp;
        const unsigned short h0 = f2bf(s0);
        const unsigned short l0 = f2bf(s0 - bf2f(h0));
        const unsigned short h1 = f2bf(s1);
        const unsigned short l1 = f2bf(s1 - bf2f(h1));
        *reinterpret_cast<unsigned int*>(ctxh + co) = (unsigned int)h0 | ((unsigned int)h1 << 16);
        *reinterpret_cast<unsigned int*>(ctxl + co) = (unsigned int)l0 | ((unsigned int)l1 << 16);
    }
}

// ---------------------------------------------------------------------------
extern "C" void kernel_launch(void* const* d_in, const int* in_sizes, int n_in,
                              void* d_out, int out_size, void* d_ws, size_t ws_size,
                              hipStream_t stream)
{
    const float* query = (const float*)d_in[0];
    const float* key   = (const float*)d_in[1];
    const float* value = (const float*)d_in[2];
    const float* Wq    = (const float*)d_in[3];
    const float* Wk    = (const float*)d_in[4];
    const float* Wv    = (const float*)d_in[5];
    const float* Wo    = (const float*)d_in[6];
    const float* bo    = (const float*)d_in[7];

    float* out   = (float*)d_out;
    float* attnO = out + (size_t)BSR * DMODEL;

    const size_t NPROJ = (size_t)BSR * DMODEL;      // 4,194,304
    const size_t NW    = (size_t)DMODEL * DMODEL;   // 1,048,576

    char* p = (char*)d_ws;
    float2* tab = (float2*)p;                 p += 1 << 20;
    ushort_t* qsh = (ushort_t*)p;             p += NPROJ * 2;
    ushort_t* qsl = (ushort_t*)p;             p += NPROJ * 2;
    ushort_t* ksh = (ushort_t*)p;             p += NPROJ * 2;
    ushort_t* ksl = (ushort_t*)p;             p += NPROJ * 2;
    ushort_t* vsh = (ushort_t*)p;             p += NPROJ * 2;
    ushort_t* vsl = (ushort_t*)p;             p += NPROJ * 2;
    ushort_t* wqh = (ushort_t*)p;             p += NW * 2;
    ushort_t* wql = (ushort_t*)p;             p += NW * 2;
    ushort_t* wkh = (ushort_t*)p;             p += NW * 2;
    ushort_t* wkl = (ushort_t*)p;             p += NW * 2;
    ushort_t* wvh = (ushort_t*)p;             p += NW * 2;
    ushort_t* wvl = (ushort_t*)p;             p += NW * 2;
    ushort_t* woh = (ushort_t*)p;             p += NW * 2;
    ushort_t* wol = (ushort_t*)p;             p += NW * 2;
    ushort_t* Vt  = (ushort_t*)p;             p += NPROJ * 2;
    // Aliases (sequential lifetimes): Q-GEMM out <- v-source; K-GEMM out <-
    // q-source; attn ctx out <- k-source.
    ushort_t* Qhi = vsh; ushort_t* Qlo = vsl;
    ushort_t* Khi = qsh; ushort_t* Klo = qsl;
    ushort_t* ctxhC = ksh; ushort_t* ctxlC = ksl;

    split_tab<<<8448, 256, 0, stream>>>(query, key, value, Wq, Wk, Wv, Wo,
                                        qsh, qsl, ksh, ksl, vsh, vsl,
                                        wqh, wql, wkh, wkl, wvh, wvl, woh, wol, tab);

    // NOTE: Q-GEMM (z=1) writes Qhi=vsh, but V-GEMM (z=0) reads vsh as input.
    // In the merged launch all three z-slices run concurrently -> the alias
    // vsh<->Qhi would RACE. Give Q its own buffers instead (ws has room).
    ushort_t* QhiX = (ushort_t*)p;            p += NPROJ * 2;
    ushort_t* QloX = (ushort_t*)p;            p += NPROJ * 2;
    // K-GEMM (z=2) writes Khi=qsh while z=1 reads qsh: same hazard -> own bufs.
    ushort_t* KhiX = (ushort_t*)p;            p += NPROJ * 2;
    ushort_t* KloX = (ushort_t*)p;            p += NPROJ * 2;

    qkv_gemm<<<dim3(16, 32, 3), 256, 0, stream>>>(qsh, qsl, ksh, ksl, vsh, vsl,
                                                  wqh, wql, wkh, wkl, wvh, wvl,
                                                  QhiX, QloX, KhiX, KloX, Vt, tab);

    attn_v6<<<dim3(2048), 1024, 0, stream>>>(QhiX, QloX, KhiX, KloX, Vt, attnO, ctxhC, ctxlC);

    gemm_out<<<dim3(16, 32), 256, 0, stream>>>(ctxhC, ctxlC, woh, wol, out, bo);
}

// Round 14
// 338.954 us; speedup vs baseline: 1.0615x; 1.0228x over previous
//
#include <hip/hip_runtime.h>
#include <cmath>

#define BB 2
#define SS 2048
#define DMODEL 1024
#define NHEADS 16
#define DK 64
#define BSR (BB*SS)          // 4096 rows

typedef float f32x4 __attribute__((ext_vector_type(4)));
typedef short s16x8 __attribute__((ext_vector_type(8)));
typedef unsigned short ushort_t;
#define MFMA_BF16 __builtin_amdgcn_mfma_f32_16x16x32_bf16

__device__ __forceinline__ unsigned short f2bf(float x) {
    unsigned int u = __float_as_uint(x);
    unsigned int r = u + 0x7FFFu + ((u >> 16) & 1u);   // RNE
    return (unsigned short)(r >> 16);
}
__device__ __forceinline__ float bf2f(unsigned short h) {
    return __uint_as_float(((unsigned int)h) << 16);
}
__device__ __forceinline__ unsigned int pk2(float lo, float hi) {
    return (unsigned int)f2bf(lo) | ((unsigned int)f2bf(hi) << 16);
}

// Fragment-tiled layouts (lane-contiguous wave loads):
// Q/K (A/B-frag): [bh][s-tile(128)][chunk(2)][grp(4)][row16][8]
__device__ __forceinline__ size_t qk_idx(int bh, int s, int d) {
    return ((((size_t)bh * 128 + (s >> 4)) * 2 + (d >> 5)) * 4 + ((d >> 3) & 3)) * 128
           + (size_t)((s & 15) * 8 + (d & 7));
}
// V^T (A-frag for PV): [bh][k-chunk(64)][dt(4)][grp(4)][row16=d][8=k]
__device__ __forceinline__ size_t v_idx(int bh, int s, int d) {
    return ((((size_t)bh * 64 + (s >> 5)) * 4 + (d >> 4)) * 4 + ((s >> 3) & 3)) * 128
           + (size_t)((d & 15) * 8 + (s & 7));
}

// ---------------------------------------------------------------------------
// split+tab: fp32 -> (hi,lo) bf16 for 3 activations + 4 weights; last 256
// blocks build the RoPE sincos table.
// ---------------------------------------------------------------------------
__global__ __launch_bounds__(256)
void split_tab(const float* __restrict__ q, const float* __restrict__ k,
               const float* __restrict__ v, const float* __restrict__ wq,
               const float* __restrict__ wk, const float* __restrict__ wv,
               const float* __restrict__ wo,
               ushort_t* qsh, ushort_t* qsl, ushort_t* ksh, ushort_t* ksl,
               ushort_t* vsh, ushort_t* vsl,
               ushort_t* wqh, ushort_t* wql, ushort_t* wkh, ushort_t* wkl,
               ushort_t* wvh, ushort_t* wvl, ushort_t* woh, ushort_t* wol,
               float2* __restrict__ tab)
{
    int blk = blockIdx.x;
    if (blk >= 8192) {                       // ---- tab tail ----
        const int t = (blk - 8192) * 256 + threadIdx.x;    // 65536
        const int s = t >> 5, j = t & 31;
        const double l2 = 13.287712379549449 / 32.0;       // log2(10000)/32
        const float invf = (float)exp2(-(double)j * l2);
        const float ang = (float)s * invf;
        tab[t] = make_float2(cosf(ang), sinf(ang));
        return;
    }
    const float* src; ushort_t* dh; ushort_t* dl;
    if      (blk < 2048) { src = q;  dh = qsh; dl = qsl; }
    else if (blk < 4096) { src = k;  dh = ksh; dl = ksl; blk -= 2048; }
    else if (blk < 6144) { src = v;  dh = vsh; dl = vsl; blk -= 4096; }
    else if (blk < 6656) { src = wq; dh = wqh; dl = wql; blk -= 6144; }
    else if (blk < 7168) { src = wk; dh = wkh; dl = wkl; blk -= 6656; }
    else if (blk < 7680) { src = wv; dh = wvh; dl = wvl; blk -= 7168; }
    else                 { src = wo; dh = woh; dl = wol; blk -= 7680; }
    const size_t off = (size_t)blk * 2048 + threadIdx.x * 8;
    float4 a = *reinterpret_cast<const float4*>(src + off);
    float4 b = *reinterpret_cast<const float4*>(src + off + 4);
    float xs[8] = {a.x, a.y, a.z, a.w, b.x, b.y, b.z, b.w};
    s16x8 hi, lo;
#pragma unroll
    for (int i = 0; i < 8; ++i) {
        unsigned short h = f2bf(xs[i]);
        hi[i] = (short)h;
        lo[i] = (short)f2bf(xs[i] - bf2f(h));
    }
    *reinterpret_cast<s16x8*>(dh + off) = hi;
    *reinterpret_cast<s16x8*>(dl + off) = lo;
}

// ---------------------------------------------------------------------------
// Merged QKV GEMM: grid (16, 32, 3); z=0: V (SINGLE-TERM bf16 -> Vt; V is
// rounded to bf16 anyway so split precision was wasted — error ~= existing
// bf16 rounding), z=1: Q (3-term + RoPE), z=2: K (3-term + RoPE).
// ---------------------------------------------------------------------------
__global__ __launch_bounds__(256)
void qkv_gemm(const ushort_t* __restrict__ qsh, const ushort_t* __restrict__ qsl,
              const ushort_t* __restrict__ ksh, const ushort_t* __restrict__ ksl,
              const ushort_t* __restrict__ vsh, const ushort_t* __restrict__ vsl,
              const ushort_t* __restrict__ wqh, const ushort_t* __restrict__ wql,
              const ushort_t* __restrict__ wkh, const ushort_t* __restrict__ wkl,
              const ushort_t* __restrict__ wvh, const ushort_t* __restrict__ wvl,
              ushort_t* __restrict__ Qhi, ushort_t* __restrict__ Qlo,
              ushort_t* __restrict__ Khi, ushort_t* __restrict__ Klo,
              ushort_t* __restrict__ Vt,
              const float2* __restrict__ tab)
{
    __shared__ __align__(16) ushort_t smAh[128 * 64];
    __shared__ __align__(16) ushort_t smAl[128 * 64];
    __shared__ __align__(16) ushort_t smBh[64 * 64];
    __shared__ __align__(16) ushort_t smBl[64 * 64];

    const int tid = threadIdx.x;
    const int lane = tid & 63;
    const int w = tid >> 6;
    const int lane16 = lane & 15;
    const int grp = (lane >> 4) & 3;
    const int m0 = blockIdx.y * 128;
    const int n0 = blockIdx.x * 64;
    const int z  = blockIdx.z;           // 0=V, 1=Q, 2=K
    const int K = 1024;
    const bool split = (z != 0);         // block-uniform

    const ushort_t* Ah = (z == 0) ? vsh : ((z == 1) ? qsh : ksh);
    const ushort_t* Al = (z == 0) ? vsl : ((z == 1) ? qsl : ksl);
    const ushort_t* Bh = (z == 0) ? wvh : ((z == 1) ? wqh : wkh);
    const ushort_t* Bl = (z == 0) ? wvl : ((z == 1) ? wql : wkl);

    f32x4 acc[2][4];
#pragma unroll
    for (int a = 0; a < 2; ++a)
#pragma unroll
        for (int e = 0; e < 4; ++e) acc[a][e] = (f32x4){0.f, 0.f, 0.f, 0.f};

    for (int k0 = 0; k0 < K; k0 += 64) {
#pragma unroll
        for (int i = 0; i < 4; ++i) {
            const int c = tid + 256 * i;
            const int row = c >> 3, gs = c & 7;
            const int dst = row * 64 + ((gs ^ (row & 7)) * 8);
            const size_t src = (size_t)(m0 + row) * K + k0 + gs * 8;
            *reinterpret_cast<s16x8*>(&smAh[dst]) = *reinterpret_cast<const s16x8*>(&Ah[src]);
            if (split)
                *reinterpret_cast<s16x8*>(&smAl[dst]) = *reinterpret_cast<const s16x8*>(&Al[src]);
        }
#pragma unroll
        for (int i = 0; i < 2; ++i) {
            const int c = tid + 256 * i;
            const int row = c >> 3, gs = c & 7;
            const int dst = row * 64 + ((gs ^ (row & 7)) * 8);
            const size_t src = (size_t)(n0 + row) * K + k0 + gs * 8;
            *reinterpret_cast<s16x8*>(&smBh[dst]) = *reinterpret_cast<const s16x8*>(&Bh[src]);
            if (split)
                *reinterpret_cast<s16x8*>(&smBl[dst]) = *reinterpret_cast<const s16x8*>(&Bl[src]);
        }
        __syncthreads();
#pragma unroll
        for (int ks = 0; ks < 2; ++ks) {
            const int slotk = ks * 4 + grp;
            s16x8 afh[2], afl[2], bfh[4], bfl[4];
#pragma unroll
            for (int mt = 0; mt < 2; ++mt) {
                const int row = w * 32 + mt * 16 + lane16;
                const int off = row * 64 + ((slotk ^ (row & 7)) * 8);
                afh[mt] = *reinterpret_cast<const s16x8*>(&smAh[off]);
                if (split) afl[mt] = *reinterpret_cast<const s16x8*>(&smAl[off]);
            }
#pragma unroll
            for (int nt = 0; nt < 4; ++nt) {
                const int row = nt * 16 + lane16;
                const int off = row * 64 + ((slotk ^ (row & 7)) * 8);
                bfh[nt] = *reinterpret_cast<const s16x8*>(&smBh[off]);
                if (split) bfl[nt] = *reinterpret_cast<const s16x8*>(&smBl[off]);
            }
#pragma unroll
            for (int mt = 0; mt < 2; ++mt)
#pragma unroll
                for (int nt = 0; nt < 4; ++nt) {
                    if (split) {
                        acc[mt][nt] = MFMA_BF16(afh[mt], bfl[nt], acc[mt][nt], 0, 0, 0);
                        acc[mt][nt] = MFMA_BF16(afl[mt], bfh[nt], acc[mt][nt], 0, 0, 0);
                    }
                    acc[mt][nt] = MFMA_BF16(afh[mt], bfh[nt], acc[mt][nt], 0, 0, 0);
                }
        }
        __syncthreads();
    }

    const int hh = blockIdx.x;               // N-tile == one head
    if (z == 0) {
#pragma unroll
        for (int mt = 0; mt < 2; ++mt)
#pragma unroll
            for (int r = 0; r < 4; ++r) {
                const int m = m0 + w * 32 + mt * 16 + grp * 4 + r;
                const int b = m >> 11, s = m & (SS - 1);
                const int bh = b * 16 + hh;
#pragma unroll
                for (int nt = 0; nt < 4; ++nt) {
                    const int d = nt * 16 + lane16;
                    Vt[v_idx(bh, s, d)] = f2bf(acc[mt][nt][r]);
                }
            }
    } else {
        ushort_t* O1 = (z == 1) ? Qhi : Khi;
        ushort_t* O2 = (z == 1) ? Qlo : Klo;
#pragma unroll
        for (int mt = 0; mt < 2; ++mt)
#pragma unroll
            for (int r = 0; r < 4; ++r) {
                const int m = m0 + w * 32 + mt * 16 + grp * 4 + r;
                const int b = m >> 11, s = m & (SS - 1);
                const int bh = b * 16 + hh;
#pragma unroll
                for (int ntp = 0; ntp < 2; ++ntp) {
                    const int j = ntp * 16 + lane16;          // 0..31
                    const float2 cs = tab[s * 32 + j];
                    const float x1 = acc[mt][ntp][r], x2 = acc[mt][ntp + 2][r];
                    const float r1 = x1 * cs.x - x2 * cs.y;
                    const float r2 = x2 * cs.x + x1 * cs.y;
                    const size_t i1 = qk_idx(bh, s, j);
                    const size_t i2 = qk_idx(bh, s, j + 32);
                    const unsigned short h1 = f2bf(r1);
                    O1[i1] = h1;  O2[i1] = f2bf(r1 - bf2f(h1));
                    const unsigned short h2 = f2bf(r2);
                    O1[i2] = h2;  O2[i2] = f2bf(r2 - bf2f(h2));
                }
            }
    }
}

// ---------------------------------------------------------------------------
// Out-projection GEMM (R8-proven, UNCHANGED): 3-term, fp32 out + bias.
// ---------------------------------------------------------------------------
__global__ __launch_bounds__(256)
void gemm_out(const ushort_t* __restrict__ Ah, const ushort_t* __restrict__ Al,
              const ushort_t* __restrict__ Bh, const ushort_t* __restrict__ Bl,
              float* __restrict__ outF, const float* __restrict__ bias)
{
    __shared__ __align__(16) ushort_t smAh[128 * 64];
    __shared__ __align__(16) ushort_t smAl[128 * 64];
    __shared__ __align__(16) ushort_t smBh[64 * 64];
    __shared__ __align__(16) ushort_t smBl[64 * 64];

    const int tid = threadIdx.x;
    const int lane = tid & 63;
    const int w = tid >> 6;
    const int lane16 = lane & 15;
    const int grp = (lane >> 4) & 3;
    const int m0 = blockIdx.y * 128;
    const int n0 = blockIdx.x * 64;
    const int K = 1024;

    f32x4 acc[2][4];
#pragma unroll
    for (int a = 0; a < 2; ++a)
#pragma unroll
        for (int e = 0; e < 4; ++e) acc[a][e] = (f32x4){0.f, 0.f, 0.f, 0.f};

    for (int k0 = 0; k0 < K; k0 += 64) {
#pragma unroll
        for (int i = 0; i < 4; ++i) {
            const int c = tid + 256 * i;
            const int row = c >> 3, gs = c & 7;
            const int dst = row * 64 + ((gs ^ (row & 7)) * 8);
            const size_t src = (size_t)(m0 + row) * K + k0 + gs * 8;
            *reinterpret_cast<s16x8*>(&smAh[dst]) = *reinterpret_cast<const s16x8*>(&Ah[src]);
            *reinterpret_cast<s16x8*>(&smAl[dst]) = *reinterpret_cast<const s16x8*>(&Al[src]);
        }
#pragma unroll
        for (int i = 0; i < 2; ++i) {
            const int c = tid + 256 * i;
            const int row = c >> 3, gs = c & 7;
            const int dst = row * 64 + ((gs ^ (row & 7)) * 8);
            const size_t src = (size_t)(n0 + row) * K + k0 + gs * 8;
            *reinterpret_cast<s16x8*>(&smBh[dst]) = *reinterpret_cast<const s16x8*>(&Bh[src]);
            *reinterpret_cast<s16x8*>(&smBl[dst]) = *reinterpret_cast<const s16x8*>(&Bl[src]);
        }
        __syncthreads();
#pragma unroll
        for (int ks = 0; ks < 2; ++ks) {
            const int slotk = ks * 4 + grp;
            s16x8 afh[2], afl[2], bfh[4], bfl[4];
#pragma unroll
            for (int mt = 0; mt < 2; ++mt) {
                const int row = w * 32 + mt * 16 + lane16;
                const int off = row * 64 + ((slotk ^ (row & 7)) * 8);
                afh[mt] = *reinterpret_cast<const s16x8*>(&smAh[off]);
                afl[mt] = *reinterpret_cast<const s16x8*>(&smAl[off]);
            }
#pragma unroll
            for (int nt = 0; nt < 4; ++nt) {
                const int row = nt * 16 + lane16;
                const int off = row * 64 + ((slotk ^ (row & 7)) * 8);
                bfh[nt] = *reinterpret_cast<const s16x8*>(&smBh[off]);
                bfl[nt] = *reinterpret_cast<const s16x8*>(&smBl[off]);
            }
#pragma unroll
            for (int mt = 0; mt < 2; ++mt)
#pragma unroll
                for (int nt = 0; nt < 4; ++nt) {
                    acc[mt][nt] = MFMA_BF16(afh[mt], bfl[nt], acc[mt][nt], 0, 0, 0);
                    acc[mt][nt] = MFMA_BF16(afl[mt], bfh[nt], acc[mt][nt], 0, 0, 0);
                    acc[mt][nt] = MFMA_BF16(afh[mt], bfh[nt], acc[mt][nt], 0, 0, 0);
                }
        }
        __syncthreads();
    }

#pragma unroll
    for (int mt = 0; mt < 2; ++mt)
#pragma unroll
        for (int r = 0; r < 4; ++r) {
            const int m = m0 + w * 32 + mt * 16 + grp * 4 + r;
#pragma unroll
            for (int nt = 0; nt < 4; ++nt) {
                const int n = n0 + nt * 16 + lane16;
                outF[(size_t)m * 1024 + n] = acc[mt][nt][r] + bias[n];
            }
        }
}

// ---------------------------------------------------------------------------
// MFMA attention v8 = v6nt + bf16-packed p (NO prefetch). pp[8][2][2] u32 =
// 32 regs vs p's 64 -> peak unified regs ~95 (v6 was ~156) -> 2 blocks/CU:
// each round's nt-store drain hides under the co-resident block's QK^T.
// Numerics proven R10/R12 (identical absmax): PV consumed bf16(p) already;
// attn store = bf16(p)*rinv.
// ---------------------------------------------------------------------------
#define SCALE_L2E 0.180336879f    // (1/8) * log2(e)

__global__ __launch_bounds__(1024, 4)
void attn_v8(const ushort_t* __restrict__ Qf_h, const ushort_t* __restrict__ Qf_l,
             const ushort_t* __restrict__ Kf_h, const ushort_t* __restrict__ Kf_l,
             const ushort_t* __restrict__ Vf,
             float* __restrict__ attn, ushort_t* __restrict__ ctxh, ushort_t* __restrict__ ctxl)
{
    __shared__ __align__(16) float slots[8][32][68];   // 69,632 B ctx reduce
    __shared__ float lsum[16][32];
    __shared__ float rinvS[32];

    const int tid = threadIdx.x;
    const int lane = tid & 63;
    const int w = tid >> 6;              // 0..15
    const int lane16 = lane & 15;
    const int grp = lane >> 4;           // 0..3

    const int bid = blockIdx.x;
    const int idx = bid >> 3;                    // 0..255
    const int bh = (bid & 7) * 4 + (idx >> 6);   // 4 bh per XCD, sequential
    const int q0 = (idx & 63) * 32;

    // ---- Q fragments: 2 q-subtiles x 2 d-chunks, hi+lo ----
    s16x8 qh[2][2], ql[2][2];
#pragma unroll
    for (int qt = 0; qt < 2; ++qt) {
        const size_t qb = ((size_t)(bh * 128 + (q0 >> 4) + qt) * 2) * 512 + lane * 8;
        qh[qt][0] = *reinterpret_cast<const s16x8*>(Qf_h + qb);
        qh[qt][1] = *reinterpret_cast<const s16x8*>(Qf_h + qb + 512);
        ql[qt][0] = *reinterpret_cast<const s16x8*>(Qf_l + qb);
        ql[qt][1] = *reinterpret_cast<const s16x8*>(Qf_l + qb + 512);
    }

    // ---- QK^T: 8 k-tiles of 16; fused exp + bf16 pack ----
    unsigned int pp[8][2][2];            // packed bf16 pairs of exp(scores)
    float lq[2] = {0.f, 0.f};
#pragma unroll
    for (int kt = 0; kt < 8; ++kt) {
        const size_t kb = ((size_t)(bh * 128 + w * 8 + kt) * 2) * 512 + lane * 8;
        const s16x8 kh0 = *reinterpret_cast<const s16x8*>(Kf_h + kb);
        const s16x8 kh1 = *reinterpret_cast<const s16x8*>(Kf_h + kb + 512);
        const s16x8 kl0 = *reinterpret_cast<const s16x8*>(Kf_l + kb);
        const s16x8 kl1 = *reinterpret_cast<const s16x8*>(Kf_l + kb + 512);
#pragma unroll
        for (int qt = 0; qt < 2; ++qt) {
            f32x4 t = {0.f, 0.f, 0.f, 0.f};
            t = MFMA_BF16(kh0, ql[qt][0], t, 0, 0, 0);
            t = MFMA_BF16(kh1, ql[qt][1], t, 0, 0, 0);
            t = MFMA_BF16(kl0, qh[qt][0], t, 0, 0, 0);
            t = MFMA_BF16(kl1, qh[qt][1], t, 0, 0, 0);
            t = MFMA_BF16(kh0, qh[qt][0], t, 0, 0, 0);
            t = MFMA_BF16(kh1, qh[qt][1], t, 0, 0, 0);
            const float e0 = exp2f(t[0] * SCALE_L2E);
            const float e1 = exp2f(t[1] * SCALE_L2E);
            const float e2 = exp2f(t[2] * SCALE_L2E);
            const float e3 = exp2f(t[3] * SCALE_L2E);
            lq[qt] += e0 + e1 + e2 + e3;
            pp[kt][qt][0] = pk2(e0, e1);
            pp[kt][qt][1] = pk2(e2, e3);
        }
    }

    // ---- cross-wave softmax denominators ----
#pragma unroll
    for (int qt = 0; qt < 2; ++qt) {
        lq[qt] += __shfl_xor(lq[qt], 16, 64);
        lq[qt] += __shfl_xor(lq[qt], 32, 64);
    }
    if (grp == 0) {
        lsum[w][lane16]      = lq[0];
        lsum[w][16 + lane16] = lq[1];
    }
    __syncthreads();                                   // b1
    float tot0 = 0.f, tot1 = 0.f;
#pragma unroll
    for (int w2 = 0; w2 < 16; ++w2) {
        tot0 += lsum[w2][lane16];
        tot1 += lsum[w2][16 + lane16];
    }
    const float rinv[2] = {1.0f / tot0, 1.0f / tot1};
    if (w == 0 && grp == 0) {
        rinvS[lane16]      = rinv[0];
        rinvS[16 + lane16] = rinv[1];
    }

    // ---- attn stores: unpack bf16 pairs, scale, NONTEMPORAL f32x4 ----
#pragma unroll
    for (int qt = 0; qt < 2; ++qt) {
        const size_t arow = ((size_t)bh * SS + q0 + qt * 16 + lane16) * SS + w * 128 + grp * 4;
#pragma unroll
        for (int kt = 0; kt < 8; ++kt) {
            const unsigned int u0 = pp[kt][qt][0];
            const unsigned int u1 = pp[kt][qt][1];
            f32x4 v4;
            v4[0] = __uint_as_float(u0 << 16) * rinv[qt];
            v4[1] = __uint_as_float(u0 & 0xffff0000u) * rinv[qt];
            v4[2] = __uint_as_float(u1 << 16) * rinv[qt];
            v4[3] = __uint_as_float(u1 & 0xffff0000u) * rinv[qt];
            __builtin_nontemporal_store(v4, reinterpret_cast<f32x4*>(&attn[arow + kt * 16]));
        }
    }

    // ---- PV: shfl redistribution directly on packed words ----
    f32x4 acc[4][2];
#pragma unroll
    for (int dt = 0; dt < 4; ++dt) {
        acc[dt][0] = (f32x4){0.f, 0.f, 0.f, 0.f};
        acc[dt][1] = (f32x4){0.f, 0.f, 0.f, 0.f};
    }
    const int src0 = lane16 + ((grp & 1) << 5);
    const int src1 = src0 + 16;
    const bool sel = (grp >> 1) != 0;
#pragma unroll
    for (int kc = 0; kc < 4; ++kc) {
        s16x8 bfr[2];
#pragma unroll
        for (int qt = 0; qt < 2; ++qt) {
            const unsigned int A0 = pp[2 * kc][qt][0];
            const unsigned int A1 = pp[2 * kc][qt][1];
            const unsigned int B0 = pp[2 * kc + 1][qt][0];
            const unsigned int B1 = pp[2 * kc + 1][qt][1];
            const unsigned int d0a = (unsigned int)__shfl((int)A0, src0, 64);
            const unsigned int d0b = (unsigned int)__shfl((int)B0, src0, 64);
            const unsigned int d1a = (unsigned int)__shfl((int)A1, src0, 64);
            const unsigned int d1b = (unsigned int)__shfl((int)B1, src0, 64);
            const unsigned int d2a = (unsigned int)__shfl((int)A0, src1, 64);
            const unsigned int d2b = (unsigned int)__shfl((int)B0, src1, 64);
            const unsigned int d3a = (unsigned int)__shfl((int)A1, src1, 64);
            const unsigned int d3b = (unsigned int)__shfl((int)B1, src1, 64);
            union { unsigned int u[4]; s16x8 v; } bu;
            bu.u[0] = sel ? d0b : d0a;
            bu.u[1] = sel ? d1b : d1a;
            bu.u[2] = sel ? d2b : d2a;
            bu.u[3] = sel ? d3b : d3a;
            bfr[qt] = bu.v;
        }
#pragma unroll
        for (int dt = 0; dt < 4; ++dt) {
            const s16x8 vf = *reinterpret_cast<const s16x8*>(
                &Vf[((size_t)(bh * 64 + w * 4 + kc) * 4 + dt) * 512 + lane * 8]);
            acc[dt][0] = MFMA_BF16(vf, bfr[0], acc[dt][0], 0, 0, 0);
            acc[dt][1] = MFMA_BF16(vf, bfr[1], acc[dt][1], 0, 0, 0);
        }
    }

    // ---- two-stage cross-wave ctx reduce ----
    if (w >= 8) {
        float* slot = &slots[w - 8][0][0];
#pragma unroll
        for (int dt = 0; dt < 4; ++dt)
#pragma unroll
            for (int qt = 0; qt < 2; ++qt) {
                f32x4 v4;
                v4[0] = acc[dt][qt][0]; v4[1] = acc[dt][qt][1];
                v4[2] = acc[dt][qt][2]; v4[3] = acc[dt][qt][3];
                *reinterpret_cast<f32x4*>(&slot[(qt * 16 + lane16) * 68 + dt * 16 + grp * 4]) = v4;
            }
    }
    __syncthreads();                                   // b2
    if (w < 8) {
        float* slot = &slots[w][0][0];
#pragma unroll
        for (int dt = 0; dt < 4; ++dt)
#pragma unroll
            for (int qt = 0; qt < 2; ++qt) {
                f32x4* pq = reinterpret_cast<f32x4*>(&slot[(qt * 16 + lane16) * 68 + dt * 16 + grp * 4]);
                f32x4 o = *pq;
                o[0] += acc[dt][qt][0]; o[1] += acc[dt][qt][1];
                o[2] += acc[dt][qt][2]; o[3] += acc[dt][qt][3];
                *pq = o;
            }
    }
    __syncthreads();                                   // b3

    // ---- final: sum 8 slots, normalize, split hi/lo, write ctx ----
    {
        const int b = bh >> 4, h = bh & 15;
        const int q = tid >> 5;              // 0..31
        const int dp = (tid & 31) * 2;       // 0..62
        float s0 = 0.f, s1 = 0.f;
#pragma unroll
        for (int s = 0; s < 8; ++s) {
            const float2 v = *reinterpret_cast<const float2*>(&slots[s][q][dp]);
            s0 += v.x; s1 += v.y;
        }
        const float rv = rinvS[q];
        s0 *= rv; s1 *= rv;
        const size_t co = ((size_t)b * SS + q0 + q) * DMODEL + h * DK + dp;
        const unsigned short h0 = f2bf(s0);
        const unsigned short l0 = f2bf(s0 - bf2f(h0));
        const unsigned short h1 = f2bf(s1);
        const unsigned short l1 = f2bf(s1 - bf2f(h1));
        *reinterpret_cast<unsigned int*>(ctxh + co) = (unsigned int)h0 | ((unsigned int)h1 << 16);
        *reinterpret_cast<unsigned int*>(ctxl + co) = (unsigned int)l0 | ((unsigned int)l1 << 16);
    }
}

// ---------------------------------------------------------------------------
extern "C" void kernel_launch(void* const* d_in, const int* in_sizes, int n_in,
                              void* d_out, int out_size, void* d_ws, size_t ws_size,
                              hipStream_t stream)
{
    const float* query = (const float*)d_in[0];
    const float* key   = (const float*)d_in[1];
    const float* value = (const float*)d_in[2];
    const float* Wq    = (const float*)d_in[3];
    const float* Wk    = (const float*)d_in[4];
    const float* Wv    = (const float*)d_in[5];
    const float* Wo    = (const float*)d_in[6];
    const float* bo    = (const float*)d_in[7];

    float* out   = (float*)d_out;
    float* attnO = out + (size_t)BSR * DMODEL;

    const size_t NPROJ = (size_t)BSR * DMODEL;      // 4,194,304
    const size_t NW    = (size_t)DMODEL * DMODEL;   // 1,048,576

    char* p = (char*)d_ws;
    float2* tab = (float2*)p;                 p += 1 << 20;
    ushort_t* qsh = (ushort_t*)p;             p += NPROJ * 2;
    ushort_t* qsl = (ushort_t*)p;             p += NPROJ * 2;
    ushort_t* ksh = (ushort_t*)p;             p += NPROJ * 2;
    ushort_t* ksl = (ushort_t*)p;             p += NPROJ * 2;
    ushort_t* vsh = (ushort_t*)p;             p += NPROJ * 2;
    ushort_t* vsl = (ushort_t*)p;             p += NPROJ * 2;
    ushort_t* wqh = (ushort_t*)p;             p += NW * 2;
    ushort_t* wql = (ushort_t*)p;             p += NW * 2;
    ushort_t* wkh = (ushort_t*)p;             p += NW * 2;
    ushort_t* wkl = (ushort_t*)p;             p += NW * 2;
    ushort_t* wvh = (ushort_t*)p;             p += NW * 2;
    ushort_t* wvl = (ushort_t*)p;             p += NW * 2;
    ushort_t* woh = (ushort_t*)p;             p += NW * 2;
    ushort_t* wol = (ushort_t*)p;             p += NW * 2;
    ushort_t* Vt  = (ushort_t*)p;             p += NPROJ * 2;
    ushort_t* ctxhC = ksh;                    // alias: k-source dead after qkv
    ushort_t* ctxlC = ksl;
    ushort_t* QhiX = (ushort_t*)p;            p += NPROJ * 2;
    ushort_t* QloX = (ushort_t*)p;            p += NPROJ * 2;
    ushort_t* KhiX = (ushort_t*)p;            p += NPROJ * 2;
    ushort_t* KloX = (ushort_t*)p;            p += NPROJ * 2;

    split_tab<<<8448, 256, 0, stream>>>(query, key, value, Wq, Wk, Wv, Wo,
                                        qsh, qsl, ksh, ksl, vsh, vsl,
                                        wqh, wql, wkh, wkl, wvh, wvl, woh, wol, tab);

    qkv_gemm<<<dim3(16, 32, 3), 256, 0, stream>>>(qsh, qsl, ksh, ksl, vsh, vsl,
                                                  wqh, wql, wkh, wkl, wvh, wvl,
                                                  QhiX, QloX, KhiX, KloX, Vt, tab);

    attn_v8<<<dim3(2048), 1024, 0, stream>>>(QhiX, QloX, KhiX, KloX, Vt, attnO, ctxhC, ctxlC);

    gemm_out<<<dim3(16, 32), 256, 0, stream>>>(ctxhC, ctxlC, woh, wol, out, bo);
}